// Round 1
// baseline (939.387 us; speedup 1.0000x reference)
//
#include <hip/hip_runtime.h>
#include <math.h>

// Shapes (fixed by the reference)
#define DXc   16
#define MRc   64
#define MBARc 256
#define NTc   9
#define DYc   8
#define HXc   1024
#define EXc   512
#define HRc   512
#define HBc   2048
#define GOUTc 64
#define TOTc  2049   // (NT-1)*MBAR + 1

__device__ __forceinline__ float fast_tanh(float x){
    // tanh(x) = 1 - 2/(exp(2x)+1); stable at both extremes
    float e = __expf(2.0f * x);
    return 1.0f - 2.0f / (e + 1.0f);
}

// ---------------- RNN: eY = scan over Y[q, k+1:, :] ----------------
__global__ void rnn_kernel(const float* __restrict__ Y, const float* __restrict__ Wih,
                           const float* __restrict__ Whh, const float* __restrict__ bh,
                           const int* kptr, const int* qptr, float* __restrict__ eY){
    __shared__ float h[HRc];
    int i = threadIdx.x;          // 512 threads
    int k = kptr[0], q = qptr[0];
    h[i] = 0.f;
    __syncthreads();
    for (int t = k + 1; t < NTc; ++t){
        float acc = bh[i];
        const float* y = Y + (q * NTc + t) * DYc;
        #pragma unroll
        for (int d = 0; d < DYc; ++d) acc += y[d] * Wih[d * HRc + i];
        for (int kk = 0; kk < HRc; ++kk) acc += h[kk] * Whh[kk * HRc + i];
        float nh = fast_tanh(acc);
        __syncthreads();
        h[i] = nh;
        __syncthreads();
    }
    eY[i] = h[i];
}

// ---------------- XW[m][c] = Xbase[m] @ Wx1 + bx1 ----------------
__global__ void xw_kernel(const float* __restrict__ X, const float* __restrict__ Wx1,
                          const float* __restrict__ bx1,
                          const int* kpptr, const int* qpptr, float* __restrict__ XW){
    int idx = blockIdx.x * 256 + threadIdx.x;   // 256*1024
    int m = idx >> 10, c = idx & 1023;
    int base = kpptr[0] * MBARc;
    const float* xr = X + ((size_t)qpptr[0] * TOTc + base + m) * DXc;
    float acc = bx1[c];
    #pragma unroll
    for (int d = 0; d < DXc; ++d) acc += xr[d] * Wx1[d * HXc + c];
    XW[idx] = acc;
}

// ---------------- SW[j][c] = stoich[:,j] @ Wx1 (row 64 = 0 for base) ----------------
__global__ void sw_kernel(const float* __restrict__ stoich, const float* __restrict__ Wx1,
                          float* __restrict__ SW){
    int idx = blockIdx.x * 256 + threadIdx.x;   // 65*1024
    int j = idx >> 10, c = idx & 1023;
    float acc = 0.f;
    if (j < MRc){
        #pragma unroll
        for (int d = 0; d < DXc; ++d) acc += stoich[d * MRc + j] * Wx1[d * HXc + c];
    }
    SW[idx] = acc;
}

// ---------------- w[j*256+m] = valid(j,m) * R_delta[m][j] ----------------
__global__ void w_kernel(const float* __restrict__ X, const float* __restrict__ R,
                         const float* __restrict__ stoich,
                         const int* kpptr, const int* qpptr, float* __restrict__ w){
    int j = blockIdx.x, m = threadIdx.x;
    int base = kpptr[0] * MBARc;
    int qp = qpptr[0];
    const float* xr = X + ((size_t)qp * TOTc + base + m) * DXc;
    bool valid = true;
    #pragma unroll
    for (int d = 0; d < DXc; ++d) valid = valid && (xr[d] + stoich[d * MRc + j] >= 0.f);
    size_t rb = (size_t)qp * TOTc * MRc;
    float rd = R[rb + (size_t)(base + 1 + m) * MRc + j] - R[rb + (size_t)(base + m) * MRc + j];
    w[j * MBARc + m] = valid ? rd : 0.f;
}

// base rows get weight -sum_j w[j][m]
__global__ void wbase_kernel(float* __restrict__ w){
    int m = threadIdx.x;
    float s = 0.f;
    for (int j = 0; j < MRc; ++j) s += w[j * MBARc + m];
    w[MRc * MBARc + m] = -s;
}

// ---------------- cY[h] = eY @ Wb1[513:1025] + bb1 ; also zero d ----------------
__global__ void cy_kernel(const float* __restrict__ eY, const float* __restrict__ Wb1,
                          const float* __restrict__ bb1, float* __restrict__ cY,
                          float* __restrict__ dacc){
    int h = blockIdx.x * 256 + threadIdx.x;   // 2048
    float acc = bb1[h];
    for (int e = 0; e < EXc; ++e) acc += eY[e] * Wb1[(size_t)(1 + EXc + e) * HBc + h];
    cY[h] = acc;
    dacc[h] = 0.f;
}

// ---------------- GEMM1: eX = tanh(XW[m]+SW[j]) @ Wx2 + bx2 ----------------
// tile 64x64, K-step 16, 256 threads, 4x4 micro-tile
__global__ __launch_bounds__(256) void gemm1_kernel(
    const float* __restrict__ XW, const float* __restrict__ SW,
    const float* __restrict__ Wx2, const float* __restrict__ bx2,
    float* __restrict__ eX){
    __shared__ __align__(16) float As[16][68];  // [kk][r]
    __shared__ __align__(16) float Bs[16][68];  // [kk][n]
    int j  = blockIdx.z;
    int m0 = blockIdx.y * 64;
    int n0 = blockIdx.x * 64;
    int tid = threadIdx.x;
    int ty = tid >> 4, tx = tid & 15;
    float acc[4][4] = {};
    const float* swr = SW + (size_t)j * HXc;
    for (int K0 = 0; K0 < HXc; K0 += 16){
        #pragma unroll
        for (int l = 0; l < 4; ++l){
            int ei = tid + l * 256;
            int r = ei >> 4, kk = ei & 15;
            float v = XW[(size_t)(m0 + r) * HXc + K0 + kk] + swr[K0 + kk];
            As[kk][r] = fast_tanh(v);
        }
        #pragma unroll
        for (int l = 0; l < 4; ++l){
            int ei = tid + l * 256;
            int kk = ei >> 6, n = ei & 63;
            Bs[kk][n] = Wx2[(size_t)(K0 + kk) * EXc + n0 + n];
        }
        __syncthreads();
        #pragma unroll
        for (int kk = 0; kk < 16; ++kk){
            float4 a = *(const float4*)&As[kk][ty * 4];
            float4 b = *(const float4*)&Bs[kk][tx * 4];
            float av[4] = {a.x, a.y, a.z, a.w};
            float bv[4] = {b.x, b.y, b.z, b.w};
            #pragma unroll
            for (int i2 = 0; i2 < 4; ++i2)
                #pragma unroll
                for (int j2 = 0; j2 < 4; ++j2)
                    acc[i2][j2] += av[i2] * bv[j2];
        }
        __syncthreads();
    }
    size_t row0 = (size_t)j * MBARc + m0;
    #pragma unroll
    for (int i2 = 0; i2 < 4; ++i2){
        int r = ty * 4 + i2;
        float4 o;
        o.x = acc[i2][0] + bx2[n0 + tx * 4 + 0];
        o.y = acc[i2][1] + bx2[n0 + tx * 4 + 1];
        o.z = acc[i2][2] + bx2[n0 + tx * 4 + 2];
        o.w = acc[i2][3] + bx2[n0 + tx * 4 + 3];
        *(float4*)&eX[(row0 + r) * EXc + n0 + tx * 4] = o;
    }
}

// ---------------- GEMM2 + fused epilogue + weighted row-reduction ----------------
// z2 = eX @ Wb1[1:513] + t[m]*Wb1[0] + cY ; d[h] += w[row]*tanh(z2[row][h])
// tile 128x128, K-step 16, 256 threads, 8x8 micro-tile
__global__ __launch_bounds__(256) void gemm2_kernel(
    const float* __restrict__ eX, const float* __restrict__ Wb1,
    const float* __restrict__ cY, const float* __restrict__ wrow,
    const float* __restrict__ times_t, const float* __restrict__ times_tau,
    const int* kptr, float* __restrict__ dacc){
    __shared__ __align__(16) float As[16][132];  // [kk][r], r<128
    __shared__ __align__(16) float Bs[16][132];  // [kk][n], n<128
    __shared__ float red[16][128];
    int jg = blockIdx.z;            // 0..64
    int m0 = blockIdx.y * 128;      // 0 or 128
    int h0 = blockIdx.x * 128;      // 0..1920
    int tid = threadIdx.x;
    int ty = tid >> 4, tx = tid & 15;
    size_t row0 = (size_t)jg * MBARc + m0;
    float acc[8][8] = {};
    for (int K0 = 0; K0 < EXc; K0 += 16){
        #pragma unroll
        for (int l = 0; l < 8; ++l){
            int ei = tid + l * 256;
            int r = ei >> 4, kk = ei & 15;
            As[kk][r] = eX[(row0 + r) * EXc + K0 + kk];
        }
        #pragma unroll
        for (int l = 0; l < 8; ++l){
            int ei = tid + l * 256;
            int kk = ei >> 7, n = ei & 127;
            Bs[kk][n] = Wb1[(size_t)(1 + K0 + kk) * HBc + h0 + n];
        }
        __syncthreads();
        #pragma unroll
        for (int kk = 0; kk < 16; ++kk){
            float4 a0 = *(const float4*)&As[kk][ty * 8];
            float4 a1 = *(const float4*)&As[kk][ty * 8 + 4];
            float4 b0 = *(const float4*)&Bs[kk][tx * 8];
            float4 b1 = *(const float4*)&Bs[kk][tx * 8 + 4];
            float av[8] = {a0.x,a0.y,a0.z,a0.w,a1.x,a1.y,a1.z,a1.w};
            float bv[8] = {b0.x,b0.y,b0.z,b0.w,b1.x,b1.y,b1.z,b1.w};
            #pragma unroll
            for (int i2 = 0; i2 < 8; ++i2)
                #pragma unroll
                for (int j2 = 0; j2 < 8; ++j2)
                    acc[i2][j2] += av[i2] * bv[j2];
        }
        __syncthreads();
    }
    int k = kptr[0];
    float tk = times_t[k];
    float w0[8], cyv[8];
    #pragma unroll
    for (int j2 = 0; j2 < 8; ++j2){
        w0[j2]  = Wb1[h0 + tx * 8 + j2];   // row 0 (t coefficient)
        cyv[j2] = cY[h0 + tx * 8 + j2];
    }
    float part[8] = {};
    #pragma unroll
    for (int i2 = 0; i2 < 8; ++i2){
        int m = m0 + ty * 8 + i2;
        float tm = tk + times_tau[m];
        float wr = wrow[row0 + ty * 8 + i2];
        #pragma unroll
        for (int j2 = 0; j2 < 8; ++j2){
            float z = acc[i2][j2] + tm * w0[j2] + cyv[j2];
            part[j2] += wr * fast_tanh(z);
        }
    }
    #pragma unroll
    for (int j2 = 0; j2 < 8; ++j2) red[ty][tx * 8 + j2] = part[j2];
    __syncthreads();
    if (tid < 128){
        float s = 0.f;
        #pragma unroll
        for (int r = 0; r < 16; ++r) s += red[r][tid];
        atomicAdd(&dacc[h0 + tid], s);
    }
}

// ---------------- si = d @ Wb2 (bb2 cancels exactly) ----------------
__global__ void out_kernel(const float* __restrict__ dacc, const float* __restrict__ Wb2,
                           float* __restrict__ out){
    __shared__ float red[4][64];
    int tid = threadIdx.x;
    int part = tid >> 6, g = tid & 63;
    float s = 0.f;
    for (int h = part * 512; h < (part + 1) * 512; ++h)
        s += dacc[h] * Wb2[(size_t)h * GOUTc + g];
    red[part][g] = s;
    __syncthreads();
    if (tid < 64)
        out[tid] = red[0][tid] + red[1][tid] + red[2][tid] + red[3][tid];
}

extern "C" void kernel_launch(void* const* d_in, const int* in_sizes, int n_in,
                              void* d_out, int out_size, void* d_ws, size_t ws_size,
                              hipStream_t stream){
    const float* X         = (const float*)d_in[0];
    const float* Y         = (const float*)d_in[1];
    const float* R         = (const float*)d_in[2];
    const float* stoich    = (const float*)d_in[3];
    const float* times_t   = (const float*)d_in[4];
    const float* times_tau = (const float*)d_in[5];
    const float* Wx1 = (const float*)d_in[6];
    const float* bx1 = (const float*)d_in[7];
    const float* Wx2 = (const float*)d_in[8];
    const float* bx2 = (const float*)d_in[9];
    const float* Wih = (const float*)d_in[10];
    const float* Whh = (const float*)d_in[11];
    const float* bh  = (const float*)d_in[12];
    const float* Wb1 = (const float*)d_in[13];
    const float* bb1 = (const float*)d_in[14];
    const float* Wb2 = (const float*)d_in[15];
    // d_in[16] = bb2: cancels in (nn_disp - nn), unused
    const int* kp  = (const int*)d_in[17];
    const int* kpp = (const int*)d_in[18];
    const int* qp  = (const int*)d_in[19];
    const int* qpp = (const int*)d_in[20];
    float* out = (float*)d_out;

    float* ws   = (float*)d_ws;
    float* eY   = ws;                 // 512
    float* cY   = ws + 512;           // 2048
    float* dacc = ws + 2560;          // 2048
    float* wrow = ws + 4608;          // 65*256 = 16640
    float* XW   = ws + 21248;         // 256*1024 = 262144
    float* SW   = ws + 283392;        // 65*1024 = 66560
    float* eXb  = ws + 349952;        // 16640*512 = 8519680  (~35.5 MB total)

    rnn_kernel  <<<1,    512, 0, stream>>>(Y, Wih, Whh, bh, kp, qp, eY);
    xw_kernel   <<<1024, 256, 0, stream>>>(X, Wx1, bx1, kpp, qpp, XW);
    sw_kernel   <<<260,  256, 0, stream>>>(stoich, Wx1, SW);
    w_kernel    <<<64,   256, 0, stream>>>(X, R, stoich, kpp, qpp, wrow);
    wbase_kernel<<<1,    256, 0, stream>>>(wrow);
    cy_kernel   <<<8,    256, 0, stream>>>(eY, Wb1, bb1, cY, dacc);
    gemm1_kernel<<<dim3(8, 4, 65),  256, 0, stream>>>(XW, SW, Wx2, bx2, eXb);
    gemm2_kernel<<<dim3(16, 2, 65), 256, 0, stream>>>(eXb, Wb1, cY, wrow, times_t, times_tau, kp, dacc);
    out_kernel  <<<1,    256, 0, stream>>>(dacc, Wb2, out);
}

// Round 3
// 420.348 us; speedup vs baseline: 2.2348x; 2.2348x over previous
//
#include <hip/hip_runtime.h>
#include <math.h>

// Shapes (fixed by the reference)
#define DXc   16
#define MRc   64
#define MBARc 256
#define NTc   9
#define DYc   8
#define HXc   1024
#define EXc   512
#define HRc   512
#define HBc   2048
#define GOUTc 64
#define TOTc  2049   // (NT-1)*MBAR + 1
#define MROWS 16384  // 64*256 displaced rows

using bf16x8 = __attribute__((ext_vector_type(8))) short;
using f32x4  = __attribute__((ext_vector_type(4))) float;

__device__ __forceinline__ float fast_tanh(float x){
    float e = __expf(2.0f * x);
    return 1.0f - 2.0f / (e + 1.0f);
}

// fp32 -> bf16 round-to-nearest-even (bit pattern in a short)
__device__ __forceinline__ short f2bf(float f){
    unsigned u = __builtin_bit_cast(unsigned, f);
    u = (u + 0x7FFFu + ((u >> 16) & 1u)) >> 16;
    return (short)u;
}

// ---------------- RNN: eY = scan over Y[q, k+1:, :] ----------------
__global__ void rnn_kernel(const float* __restrict__ Y, const float* __restrict__ Wih,
                           const float* __restrict__ Whh, const float* __restrict__ bh,
                           const int* kptr, const int* qptr, float* __restrict__ eY){
    __shared__ float h[HRc];
    int i = threadIdx.x;          // 512 threads
    int k = kptr[0], q = qptr[0];
    h[i] = 0.f;
    __syncthreads();
    for (int t = k + 1; t < NTc; ++t){
        float acc = bh[i];
        const float* y = Y + (q * NTc + t) * DYc;
        #pragma unroll
        for (int d = 0; d < DYc; ++d) acc += y[d] * Wih[d * HRc + i];
        for (int kk = 0; kk < HRc; ++kk) acc += h[kk] * Whh[kk * HRc + i];
        float nh = fast_tanh(acc);
        __syncthreads();
        h[i] = nh;
        __syncthreads();
    }
    eY[i] = h[i];
}

// ---------------- SW[j][c] = stoich[:,j] @ Wx1 (j<64) ----------------
__global__ void sw_kernel(const float* __restrict__ stoich, const float* __restrict__ Wx1,
                          float* __restrict__ SW){
    int idx = blockIdx.x * 256 + threadIdx.x;   // 64*1024
    int j = idx >> 10, c = idx & 1023;
    float acc = 0.f;
    #pragma unroll
    for (int d = 0; d < DXc; ++d) acc += stoich[d * MRc + j] * Wx1[d * HXc + c];
    SW[idx] = acc;
}

// ---------------- w[j*256+m] = valid(j,m) * R_delta[m][j] ----------------
__global__ void w_kernel(const float* __restrict__ X, const float* __restrict__ R,
                         const float* __restrict__ stoich,
                         const int* kpptr, const int* qpptr, float* __restrict__ w){
    int j = blockIdx.x, m = threadIdx.x;
    int base = kpptr[0] * MBARc;
    int qp = qpptr[0];
    const float* xr = X + ((size_t)qp * TOTc + base + m) * DXc;
    bool valid = true;
    #pragma unroll
    for (int d = 0; d < DXc; ++d) valid = valid && (xr[d] + stoich[d * MRc + j] >= 0.f);
    size_t rb = (size_t)qp * TOTc * MRc;
    float rd = R[rb + (size_t)(base + 1 + m) * MRc + j] - R[rb + (size_t)(base + m) * MRc + j];
    w[j * MBARc + m] = valid ? rd : 0.f;
}

// ---------------- cY[h] = eY @ Wb1[513:1025] + bb1 ; also zero dacc ----------------
__global__ void cy_kernel(const float* __restrict__ eY, const float* __restrict__ Wb1,
                          const float* __restrict__ bb1, float* __restrict__ cY,
                          float* __restrict__ dacc){
    int h = blockIdx.x * 256 + threadIdx.x;   // 2048
    float acc = bb1[h];
    for (int e = 0; e < EXc; ++e) acc += eY[e] * Wb1[(size_t)(1 + EXc + e) * HBc + h];
    cY[h] = acc;
    dacc[h] = 0.f;
}

// ---------------- XW[m][c] = Xbase[m]@Wx1 + bx1 ; T1 = tanh(XW) (fp32 base) ----------------
__global__ void xwt1_kernel(const float* __restrict__ X, const float* __restrict__ Wx1,
                            const float* __restrict__ bx1,
                            const int* kpptr, const int* qpptr,
                            float* __restrict__ XW, float* __restrict__ T1){
    int idx = blockIdx.x * 256 + threadIdx.x;   // 256*1024
    int m = idx >> 10, c = idx & 1023;
    int base = kpptr[0] * MBARc;
    const float* xr = X + ((size_t)qpptr[0] * TOTc + base + m) * DXc;
    float acc = bx1[c];
    #pragma unroll
    for (int d = 0; d < DXc; ++d) acc += xr[d] * Wx1[d * HXc + c];
    XW[idx] = acc;
    T1[idx] = fast_tanh(acc);
}

// ---------------- pack Wx2 (1024x512) into MFMA B-fragment order, KT=32 ----------------
__global__ void pack_wx2_kernel(const float* __restrict__ Wx2, short* __restrict__ Bp){
    size_t grp = (size_t)blockIdx.x * 256 + threadIdx.x;  // 65536 groups
    int lane = grp & 63;
    size_t t2 = grp >> 6;
    int kt = t2 & 31;
    int nt = t2 >> 5;
    int n  = nt * 16 + (lane & 15);
    int k0 = kt * 32 + ((lane >> 4) << 3);
    short out[8];
    #pragma unroll
    for (int jj = 0; jj < 8; ++jj) out[jj] = f2bf(Wx2[(size_t)(k0 + jj) * EXc + n]);
    *(bf16x8*)(Bp + grp * 8) = *(bf16x8*)out;
}

// ---------------- pack Wb1 rows 1..512 (K=512 x N=2048) into B-fragment order, KT=16 ----------------
__global__ void pack_wb1_kernel(const float* __restrict__ Wb1, short* __restrict__ Bp){
    size_t grp = (size_t)blockIdx.x * 256 + threadIdx.x;  // 131072 groups
    int lane = grp & 63;
    size_t t2 = grp >> 6;
    int kt = t2 & 15;
    int nt = t2 >> 4;
    int n  = nt * 16 + (lane & 15);
    int k0 = kt * 32 + ((lane >> 4) << 3);
    short out[8];
    #pragma unroll
    for (int jj = 0; jj < 8; ++jj) out[jj] = f2bf(Wb1[(size_t)(1 + k0 + jj) * HBc + n]);
    *(bf16x8*)(Bp + grp * 8) = *(bf16x8*)out;
}

// ---------------- eXbase[m][e] = T1[m] @ Wx2 + bx2  (fp32, 256x512) ----------------
__global__ __launch_bounds__(256) void exbase_kernel(const float* __restrict__ T1,
                                                     const float* __restrict__ Wx2,
                                                     const float* __restrict__ bx2,
                                                     float* __restrict__ eXb){
    __shared__ float t1s[8 * 1024];
    int tid = threadIdx.x;
    int e = blockIdx.x * 256 + tid;
    int m0 = blockIdx.y * 8;
    #pragma unroll
    for (int l = 0; l < 32; ++l){
        int idx = tid + l * 256;
        t1s[idx] = T1[(size_t)(m0 + (idx >> 10)) * HXc + (idx & 1023)];
    }
    __syncthreads();
    float acc[8] = {};
    for (int kk = 0; kk < HXc; ++kk){
        float wv = Wx2[(size_t)kk * EXc + e];
        #pragma unroll
        for (int mm = 0; mm < 8; ++mm) acc[mm] += t1s[mm * 1024 + kk] * wv;
    }
    float be = bx2[e];
    #pragma unroll
    for (int mm = 0; mm < 8; ++mm) eXb[(size_t)(m0 + mm) * EXc + e] = acc[mm] + be;
}

// ---------------- Z2B[m][h] = eXbase[m]@Wb1[1:513] + t[m]*Wb1[0] + cY ; TB = tanh(Z2B) ----------------
__global__ __launch_bounds__(256) void z2base_kernel(const float* __restrict__ eXb,
                                                     const float* __restrict__ Wb1,
                                                     const float* __restrict__ cY,
                                                     const float* __restrict__ times_t,
                                                     const float* __restrict__ times_tau,
                                                     const int* kptr,
                                                     float* __restrict__ Z2B,
                                                     float* __restrict__ TB){
    __shared__ float exs[8 * 512];
    int tid = threadIdx.x;
    int h = blockIdx.x * 256 + tid;
    int m0 = blockIdx.y * 8;
    #pragma unroll
    for (int l = 0; l < 16; ++l){
        int idx = tid + l * 256;
        exs[idx] = eXb[(size_t)(m0 + (idx >> 9)) * EXc + (idx & 511)];
    }
    __syncthreads();
    float acc[8] = {};
    for (int kk = 0; kk < EXc; ++kk){
        float wv = Wb1[(size_t)(1 + kk) * HBc + h];
        #pragma unroll
        for (int mm = 0; mm < 8; ++mm) acc[mm] += exs[mm * 512 + kk] * wv;
    }
    float tk = times_t[kptr[0]];
    float w0 = Wb1[h], cy = cY[h];
    #pragma unroll
    for (int mm = 0; mm < 8; ++mm){
        int m = m0 + mm;
        float z = acc[mm] + (tk + times_tau[m]) * w0 + cy;
        Z2B[(size_t)m * HBc + h] = z;
        TB[(size_t)m * HBc + h] = fast_tanh(z);
    }
}

// ---------------- act_delta: A1p = bf16(tanh(XW+SW[j]) - T1), packed A-layout, KT=32 ----------------
__global__ void act_delta_kernel(const float* __restrict__ XW, const float* __restrict__ T1,
                                 const float* __restrict__ SW, short* __restrict__ A1p){
    size_t grp = (size_t)blockIdx.x * 256 + threadIdx.x;  // 2,097,152 groups
    int lane = grp & 63;
    size_t t2 = grp >> 6;      // = mt*32 + kt
    int kt = t2 & 31;
    int mt = (int)(t2 >> 5);              // 0..1023
    int m  = mt * 16 + (lane & 15);       // global row 0..16383
    int c0 = kt * 32 + ((lane >> 4) << 3);
    int j    = m >> 8;
    int mloc = m & 255;
    const float* xwr = XW + (size_t)mloc * HXc + c0;
    const float* t1r = T1 + (size_t)mloc * HXc + c0;
    const float* swr = SW + (size_t)j * HXc + c0;
    short out[8];
    #pragma unroll
    for (int i = 0; i < 8; ++i)
        out[i] = f2bf(fast_tanh(xwr[i] + swr[i]) - t1r[i]);
    *(bf16x8*)(A1p + grp * 8) = *(bf16x8*)out;
}

// ---- shared MFMA macros: load frag quads + 4x4 MFMA grid ----
#define LDFRAG(aa, bb, kk) {                                                              \
    _Pragma("unroll") for (int i_ = 0; i_ < 4; ++i_)                                      \
        aa[i_] = *(const bf16x8*)(Ap + (((size_t)(mt0 + i_) * KT + (kk)) * 64 + lane) * 8); \
    _Pragma("unroll") for (int i_ = 0; i_ < 4; ++i_)                                      \
        bb[i_] = *(const bf16x8*)(Bp + (((size_t)(nt0 + i_) * KT + (kk)) * 64 + lane) * 8); }
#define MMGRID(aa, bb) {                                                                  \
    _Pragma("unroll") for (int i_ = 0; i_ < 4; ++i_)                                      \
        _Pragma("unroll") for (int j_ = 0; j_ < 4; ++j_)                                  \
            acc[i_][j_] = __builtin_amdgcn_mfma_f32_16x16x32_bf16(aa[i_], bb[j_], acc[i_][j_], 0, 0, 0); }

// ---------------- GEMM1 (MFMA): dXp = A1p @ Wx2p  (no bias; repacked as gemm2 A, KT2=16) ----------------
// M=16384, N=512, K=1024. 128x128 tiles, 4 waves (2x2), 16 frags/wave.
__global__ __launch_bounds__(256) void gemm1b_mfma(
    const short* __restrict__ Ap, const short* __restrict__ Bp,
    short* __restrict__ dXp){
    const int KT = 32;
    int tid = threadIdx.x;
    int wave = tid >> 6, lane = tid & 63;
    int wm = wave >> 1, wn = wave & 1;
    int bm = blockIdx.y, bn = blockIdx.x;
    int mt0 = bm * 8 + wm * 4;
    int nt0 = bn * 8 + wn * 4;
    int lhi = lane >> 4, llo = lane & 15;
    f32x4 acc[4][4];
    #pragma unroll
    for (int i = 0; i < 4; ++i)
        #pragma unroll
        for (int j = 0; j < 4; ++j) acc[i][j] = (f32x4){0.f, 0.f, 0.f, 0.f};
    bf16x8 a0[4], b0[4], a1[4], b1[4];
    LDFRAG(a0, b0, 0);
    for (int kt = 0; kt < KT - 2; kt += 2){
        LDFRAG(a1, b1, kt + 1);
        MMGRID(a0, b0);
        LDFRAG(a0, b0, kt + 2);
        MMGRID(a1, b1);
    }
    LDFRAG(a1, b1, KT - 1);
    MMGRID(a0, b0);
    MMGRID(a1, b1);
    #pragma unroll
    for (int j = 0; j < 4; ++j){
        int e = bn * 128 + wn * 64 + j * 16 + llo;
        int kt2 = e >> 5, hi2 = (e >> 3) & 3, jj = e & 7;
        #pragma unroll
        for (int i = 0; i < 4; ++i){
            #pragma unroll
            for (int r = 0; r < 4; ++r){
                int m = bm * 128 + wm * 64 + i * 16 + lhi * 4 + r;
                int mt2 = m >> 4, lo2 = m & 15;
                dXp[(((size_t)mt2 * 16 + kt2) * 64 + hi2 * 16 + lo2) * 8 + jj] =
                    f2bf(acc[i][j][r]);
            }
        }
    }
}

// ---------------- GEMM2 (MFMA): Dz2 = dXp @ Wb1p ; fused tanh-difference reduction ----------------
// M=16384, N=2048, K=512. dacc[n] += sum_m w[m]*(tanh(zb+Dz2)-tanh(zb))
__global__ __launch_bounds__(256) void gemm2b_mfma(
    const short* __restrict__ Ap, const short* __restrict__ Bp,
    const float* __restrict__ Z2B, const float* __restrict__ TB,
    const float* __restrict__ wrow, float* __restrict__ dacc){
    const int KT = 16;
    int tid = threadIdx.x;
    int wave = tid >> 6, lane = tid & 63;
    int wm = wave >> 1, wn = wave & 1;
    int bm = blockIdx.y, bn = blockIdx.x;
    int mt0 = bm * 8 + wm * 4;
    int nt0 = bn * 8 + wn * 4;
    int lhi = lane >> 4, llo = lane & 15;
    f32x4 acc[4][4];
    #pragma unroll
    for (int i = 0; i < 4; ++i)
        #pragma unroll
        for (int j = 0; j < 4; ++j) acc[i][j] = (f32x4){0.f, 0.f, 0.f, 0.f};
    bf16x8 a0[4], b0[4], a1[4], b1[4];
    LDFRAG(a0, b0, 0);
    for (int kt = 0; kt < KT - 2; kt += 2){
        LDFRAG(a1, b1, kt + 1);
        MMGRID(a0, b0);
        LDFRAG(a0, b0, kt + 2);
        MMGRID(a1, b1);
    }
    LDFRAG(a1, b1, KT - 1);
    MMGRID(a0, b0);
    MMGRID(a1, b1);
    // fused epilogue: tanh difference against fp32 base tables
    int nj[4];
    #pragma unroll
    for (int j = 0; j < 4; ++j) nj[j] = bn * 128 + wn * 64 + j * 16 + llo;
    float part[4] = {0.f, 0.f, 0.f, 0.f};
    #pragma unroll
    for (int i = 0; i < 4; ++i){
        #pragma unroll
        for (int r = 0; r < 4; ++r){
            int m = bm * 128 + wm * 64 + i * 16 + lhi * 4 + r;
            float wr = wrow[m];
            int mloc = m & 255;
            const float* zrow = Z2B + (size_t)mloc * HBc;
            const float* trow = TB  + (size_t)mloc * HBc;
            #pragma unroll
            for (int j = 0; j < 4; ++j){
                float dz = acc[i][j][r];
                part[j] += wr * (fast_tanh(zrow[nj[j]] + dz) - trow[nj[j]]);
            }
        }
    }
    #pragma unroll
    for (int j = 0; j < 4; ++j){
        part[j] += __shfl_xor(part[j], 16);
        part[j] += __shfl_xor(part[j], 32);
    }
    __shared__ float redn[128];
    if (tid < 128) redn[tid] = 0.f;
    __syncthreads();
    if (lane < 16){
        #pragma unroll
        for (int j = 0; j < 4; ++j)
            atomicAdd(&redn[wn * 64 + j * 16 + llo], part[j]);
    }
    __syncthreads();
    if (tid < 128) atomicAdd(&dacc[bn * 128 + tid], redn[tid]);
}

// ---------------- si = dacc @ Wb2 (bb2 cancels exactly) ----------------
__global__ void out_kernel(const float* __restrict__ dacc, const float* __restrict__ Wb2,
                           float* __restrict__ out){
    __shared__ float red[4][64];
    int tid = threadIdx.x;
    int part = tid >> 6, g = tid & 63;
    float s = 0.f;
    for (int h = part * 512; h < (part + 1) * 512; ++h)
        s += dacc[h] * Wb2[(size_t)h * GOUTc + g];
    red[part][g] = s;
    __syncthreads();
    if (tid < 64)
        out[tid] = red[0][tid] + red[1][tid] + red[2][tid] + red[3][tid];
}

extern "C" void kernel_launch(void* const* d_in, const int* in_sizes, int n_in,
                              void* d_out, int out_size, void* d_ws, size_t ws_size,
                              hipStream_t stream){
    const float* X         = (const float*)d_in[0];
    const float* Y         = (const float*)d_in[1];
    const float* R         = (const float*)d_in[2];
    const float* stoich    = (const float*)d_in[3];
    const float* times_t   = (const float*)d_in[4];
    const float* times_tau = (const float*)d_in[5];
    const float* Wx1 = (const float*)d_in[6];
    const float* bx1 = (const float*)d_in[7];
    const float* Wx2 = (const float*)d_in[8];
    const float* bx2 = (const float*)d_in[9];
    const float* Wih = (const float*)d_in[10];
    const float* Whh = (const float*)d_in[11];
    const float* bh  = (const float*)d_in[12];
    const float* Wb1 = (const float*)d_in[13];
    const float* bb1 = (const float*)d_in[14];
    const float* Wb2 = (const float*)d_in[15];
    // d_in[16] = bb2: cancels in (nn_disp - nn), unused
    const int* kp  = (const int*)d_in[17];
    const int* kpp = (const int*)d_in[18];
    const int* qp  = (const int*)d_in[19];
    const int* qpp = (const int*)d_in[20];
    float* out = (float*)d_out;

    float* ws   = (float*)d_ws;
    float* eY   = ws;                        // 512
    float* cY   = ws + 512;                  // 2048
    float* dacc = ws + 2560;                 // 2048
    float* wrow = ws + 4608;                 // 64*256 = 16384
    float* SW   = ws + 20992;                // 64*1024 = 65536
    float* XW   = ws + 86528;                // 256*1024 = 262144
    float* T1   = ws + 348672;               // 256*1024 = 262144
    float* eXb  = ws + 610816;               // 256*512 = 131072
    float* Z2B  = ws + 741888;               // 256*2048 = 524288
    float* TB   = ws + 1266176;              // 256*2048 = 524288
    short* A1p  = (short*)(ws + 1790464);    // 16384*1024 bf16 = 8,388,608 float slots
    short* Wx2p = (short*)(ws + 10179072);   // 1024*512 bf16 = 262,144 float slots
    short* Wb1p = (short*)(ws + 10441216);   // 512*2048 bf16 = 524,288 float slots
    short* dXp  = (short*)(ws + 10965504);   // 16384*512 bf16 = 4,194,304 float slots
    // total ws use: 15,159,808 floats = 60.6 MB

    rnn_kernel      <<<1,    512, 0, stream>>>(Y, Wih, Whh, bh, kp, qp, eY);
    sw_kernel       <<<256,  256, 0, stream>>>(stoich, Wx1, SW);
    w_kernel        <<<64,   256, 0, stream>>>(X, R, stoich, kpp, qpp, wrow);
    cy_kernel       <<<8,    256, 0, stream>>>(eY, Wb1, bb1, cY, dacc);
    xwt1_kernel     <<<1024, 256, 0, stream>>>(X, Wx1, bx1, kpp, qpp, XW, T1);
    pack_wx2_kernel <<<256,  256, 0, stream>>>(Wx2, Wx2p);
    pack_wb1_kernel <<<512,  256, 0, stream>>>(Wb1, Wb1p);
    exbase_kernel   <<<dim3(2, 32),  256, 0, stream>>>(T1, Wx2, bx2, eXb);
    z2base_kernel   <<<dim3(8, 32),  256, 0, stream>>>(eXb, Wb1, cY, times_t, times_tau, kp, Z2B, TB);
    act_delta_kernel<<<8192, 256, 0, stream>>>(XW, T1, SW, A1p);
    gemm1b_mfma     <<<dim3(4, 128),  256, 0, stream>>>(A1p, Wx2p, dXp);
    gemm2b_mfma     <<<dim3(16, 128), 256, 0, stream>>>(dXp, Wb1p, Z2B, TB, wrow, dacc);
    out_kernel      <<<1,    256, 0, stream>>>(dacc, Wb2, out);
}

// Round 4
// 412.635 us; speedup vs baseline: 2.2766x; 1.0187x over previous
//
#include <hip/hip_runtime.h>
#include <math.h>

// Shapes (fixed by the reference)
#define DXc   16
#define MRc   64
#define MBARc 256
#define NTc   9
#define DYc   8
#define HXc   1024
#define EXc   512
#define HRc   512
#define HBc   2048
#define GOUTc 64
#define TOTc  2049   // (NT-1)*MBAR + 1

using bf16x8 = __attribute__((ext_vector_type(8))) short;
using f32x4  = __attribute__((ext_vector_type(4))) float;

typedef unsigned int u32;
typedef u32 __attribute__((address_space(1))) gbl_u32;
typedef u32 __attribute__((address_space(3))) lds_u32;

__device__ __forceinline__ float fast_tanh(float x){
    float e = __expf(2.0f * x);
    return 1.0f - 2.0f / (e + 1.0f);
}

// fp32 -> bf16 round-to-nearest-even (bit pattern in a short)
__device__ __forceinline__ short f2bf(float f){
    unsigned u = __builtin_bit_cast(unsigned, f);
    u = (u + 0x7FFFu + ((u >> 16) & 1u)) >> 16;
    return (short)u;
}

// async global->LDS, 16 B per lane; LDS dest = wave-uniform base + lane*16
__device__ __forceinline__ void gld_lds16(const short* g, short* l){
    __builtin_amdgcn_global_load_lds((const gbl_u32*)g, (lds_u32*)l, 16, 0, 0);
}

// ---------------- RNN step kernels ----------------
__global__ void rnn_init_kernel(float* __restrict__ h0){
    h0[threadIdx.x] = 0.f;   // 512 threads
}

// one scan step: h_next = tanh(y_t@Wih + h_cur@Whh + bh); pass-through if t out of range
// grid 8 blocks x 512 threads; block handles 64 outputs, 8-way split-k
__global__ __launch_bounds__(512) void rnn_step_kernel(
    const float* __restrict__ Y, const float* __restrict__ Wih,
    const float* __restrict__ Whh, const float* __restrict__ bh,
    const int* kptr, const int* qptr,
    const float* __restrict__ h_cur, float* __restrict__ h_next, int step){
    __shared__ float hs[HRc];
    __shared__ float psum[8][64];
    int tid = threadIdx.x;
    int o   = tid & 63;
    int seg = tid >> 6;                 // 0..7
    int out = blockIdx.x * 64 + o;
    int k = kptr[0], q = qptr[0];
    int t = k + 1 + step;
    hs[tid] = h_cur[tid];
    __syncthreads();
    if (t >= NTc){                      // uniform branch
        if (seg == 0) h_next[out] = hs[out];
        return;
    }
    int k0 = seg * 64;
    float a0 = 0.f, a1 = 0.f, a2 = 0.f, a3 = 0.f;
    #pragma unroll 4
    for (int kk = 0; kk < 64; kk += 4){
        a0 += hs[k0 + kk + 0] * Whh[(size_t)(k0 + kk + 0) * HRc + out];
        a1 += hs[k0 + kk + 1] * Whh[(size_t)(k0 + kk + 1) * HRc + out];
        a2 += hs[k0 + kk + 2] * Whh[(size_t)(k0 + kk + 2) * HRc + out];
        a3 += hs[k0 + kk + 3] * Whh[(size_t)(k0 + kk + 3) * HRc + out];
    }
    psum[seg][o] = (a0 + a1) + (a2 + a3);
    __syncthreads();
    if (seg == 0){
        float a = 0.f;
        #pragma unroll
        for (int r = 0; r < 8; ++r) a += psum[r][o];
        const float* y = Y + (q * NTc + t) * DYc;
        float z = bh[out];
        #pragma unroll
        for (int d = 0; d < DYc; ++d) z += y[d] * Wih[d * HRc + out];
        h_next[out] = fast_tanh(z + a);
    }
}

// ---------------- merged weight-prep: SW + pack Wx2 + pack Wb1 ----------------
__global__ void pack_static_kernel(const float* __restrict__ stoich, const float* __restrict__ Wx1,
                                   const float* __restrict__ Wx2, const float* __restrict__ Wb1,
                                   float* __restrict__ SW, short* __restrict__ Wx2p,
                                   short* __restrict__ Wb1p){
    int b = blockIdx.x, tid = threadIdx.x;
    if (b < 256){
        // SW[j][c] = stoich[:,j] @ Wx1, 64*1024 elems
        int idx = b * 256 + tid;
        int j = idx >> 10, c = idx & 1023;
        float acc = 0.f;
        #pragma unroll
        for (int d = 0; d < DXc; ++d) acc += stoich[d * MRc + j] * Wx1[d * HXc + c];
        SW[idx] = acc;
    } else if (b < 512){
        // pack Wx2 (1024x512) into B-fragment order, KTOT=32
        size_t grp = (size_t)(b - 256) * 256 + tid;    // 65536 groups
        int lane = grp & 63;
        size_t t2 = grp >> 6;
        int kt = t2 & 31, nt = t2 >> 5;
        int n  = nt * 16 + (lane & 15);
        int k0 = kt * 32 + ((lane >> 4) << 3);
        short o8[8];
        #pragma unroll
        for (int jj = 0; jj < 8; ++jj) o8[jj] = f2bf(Wx2[(size_t)(k0 + jj) * EXc + n]);
        *(bf16x8*)(Wx2p + grp * 8) = *(bf16x8*)o8;
    } else {
        // pack Wb1 rows 1..512 (512x2048) into B-fragment order, KTOT=16
        size_t grp = (size_t)(b - 512) * 256 + tid;    // 131072 groups
        int lane = grp & 63;
        size_t t2 = grp >> 6;
        int kt = t2 & 15, nt = t2 >> 4;
        int n  = nt * 16 + (lane & 15);
        int k0 = kt * 32 + ((lane >> 4) << 3);
        short o8[8];
        #pragma unroll
        for (int jj = 0; jj < 8; ++jj) o8[jj] = f2bf(Wb1[(size_t)(1 + k0 + jj) * HBc + n]);
        *(bf16x8*)(Wb1p + grp * 8) = *(bf16x8*)o8;
    }
}

// ---------------- w[j*256+m] = valid(j,m) * R_delta[m][j] ----------------
__global__ void w_kernel(const float* __restrict__ X, const float* __restrict__ R,
                         const float* __restrict__ stoich,
                         const int* kpptr, const int* qpptr, float* __restrict__ w){
    int j = blockIdx.x, m = threadIdx.x;
    int base = kpptr[0] * MBARc;
    int qp = qpptr[0];
    const float* xr = X + ((size_t)qp * TOTc + base + m) * DXc;
    bool valid = true;
    #pragma unroll
    for (int d = 0; d < DXc; ++d) valid = valid && (xr[d] + stoich[d * MRc + j] >= 0.f);
    size_t rb = (size_t)qp * TOTc * MRc;
    float rd = R[rb + (size_t)(base + 1 + m) * MRc + j] - R[rb + (size_t)(base + m) * MRc + j];
    w[j * MBARc + m] = valid ? rd : 0.f;
}

// ---------------- cY[h] = eY @ Wb1[513:1025] + bb1 ; also zero dacc ----------------
__global__ void cy_kernel(const float* __restrict__ eY, const float* __restrict__ Wb1,
                          const float* __restrict__ bb1, float* __restrict__ cY,
                          float* __restrict__ dacc){
    int h = blockIdx.x * 256 + threadIdx.x;   // 2048
    float acc = bb1[h];
    for (int e = 0; e < EXc; ++e) acc += eY[e] * Wb1[(size_t)(1 + EXc + e) * HBc + h];
    cY[h] = acc;
    dacc[h] = 0.f;
}

// ---------------- XW[m][c] = Xbase[m]@Wx1 + bx1 ; T1 = tanh(XW) ----------------
__global__ void xwt1_kernel(const float* __restrict__ X, const float* __restrict__ Wx1,
                            const float* __restrict__ bx1,
                            const int* kpptr, const int* qpptr,
                            float* __restrict__ XW, float* __restrict__ T1){
    int idx = blockIdx.x * 256 + threadIdx.x;   // 256*1024
    int m = idx >> 10, c = idx & 1023;
    int base = kpptr[0] * MBARc;
    const float* xr = X + ((size_t)qpptr[0] * TOTc + base + m) * DXc;
    float acc = bx1[c];
    #pragma unroll
    for (int d = 0; d < DXc; ++d) acc += xr[d] * Wx1[d * HXc + c];
    XW[idx] = acc;
    T1[idx] = fast_tanh(acc);
}

// ---------------- eXbase[m][e] = T1[m] @ Wx2 + bx2  (fp32, 256x512) ----------------
__global__ __launch_bounds__(256) void exbase_kernel(const float* __restrict__ T1,
                                                     const float* __restrict__ Wx2,
                                                     const float* __restrict__ bx2,
                                                     float* __restrict__ eXb){
    __shared__ float t1s[8 * 1024];
    int tid = threadIdx.x;
    int e = blockIdx.x * 256 + tid;
    int m0 = blockIdx.y * 8;
    #pragma unroll
    for (int l = 0; l < 32; ++l){
        int idx = tid + l * 256;
        t1s[idx] = T1[(size_t)(m0 + (idx >> 10)) * HXc + (idx & 1023)];
    }
    __syncthreads();
    float acc[8] = {};
    for (int kk = 0; kk < HXc; ++kk){
        float wv = Wx2[(size_t)kk * EXc + e];
        #pragma unroll
        for (int mm = 0; mm < 8; ++mm) acc[mm] += t1s[mm * 1024 + kk] * wv;
    }
    float be = bx2[e];
    #pragma unroll
    for (int mm = 0; mm < 8; ++mm) eXb[(size_t)(m0 + mm) * EXc + e] = acc[mm] + be;
}

// ---------------- Z2B[m][h] = eXbase[m]@Wb1[1:513] + t[m]*Wb1[0] + cY ; TB = tanh ----------------
__global__ __launch_bounds__(256) void z2base_kernel(const float* __restrict__ eXb,
                                                     const float* __restrict__ Wb1,
                                                     const float* __restrict__ cY,
                                                     const float* __restrict__ times_t,
                                                     const float* __restrict__ times_tau,
                                                     const int* kptr,
                                                     float* __restrict__ Z2B,
                                                     float* __restrict__ TB){
    __shared__ float exs[8 * 512];
    int tid = threadIdx.x;
    int h = blockIdx.x * 256 + tid;
    int m0 = blockIdx.y * 8;
    #pragma unroll
    for (int l = 0; l < 16; ++l){
        int idx = tid + l * 256;
        exs[idx] = eXb[(size_t)(m0 + (idx >> 9)) * EXc + (idx & 511)];
    }
    __syncthreads();
    float acc[8] = {};
    for (int kk = 0; kk < EXc; ++kk){
        float wv = Wb1[(size_t)(1 + kk) * HBc + h];
        #pragma unroll
        for (int mm = 0; mm < 8; ++mm) acc[mm] += exs[mm * 512 + kk] * wv;
    }
    float tk = times_t[kptr[0]];
    float w0 = Wb1[h], cy = cY[h];
    #pragma unroll
    for (int mm = 0; mm < 8; ++mm){
        int m = m0 + mm;
        float z = acc[mm] + (tk + times_tau[m]) * w0 + cy;
        Z2B[(size_t)m * HBc + h] = z;
        TB[(size_t)m * HBc + h] = fast_tanh(z);
    }
}

// ---------------- act_delta: A1p = bf16(tanh(XW+SW[j]) - T1), packed A-layout, KTOT=32 ----------------
__global__ void act_delta_kernel(const float* __restrict__ XW, const float* __restrict__ T1,
                                 const float* __restrict__ SW, short* __restrict__ A1p){
    size_t grp = (size_t)blockIdx.x * 256 + threadIdx.x;  // 2,097,152 groups
    int lane = grp & 63;
    size_t t2 = grp >> 6;      // = mt*32 + kt
    int kt = t2 & 31;
    int mt = (int)(t2 >> 5);              // 0..1023
    int m  = mt * 16 + (lane & 15);       // global row 0..16383
    int c0 = kt * 32 + ((lane >> 4) << 3);
    int j    = m >> 8;
    int mloc = m & 255;
    const float* xwr = XW + (size_t)mloc * HXc + c0;
    const float* t1r = T1 + (size_t)mloc * HXc + c0;
    const float* swr = SW + (size_t)j * HXc + c0;
    short o8[8];
    #pragma unroll
    for (int i = 0; i < 8; ++i)
        o8[i] = f2bf(fast_tanh(xwr[i] + swr[i]) - t1r[i]);
    *(bf16x8*)(A1p + grp * 8) = *(bf16x8*)o8;
}

// ---- MFMA helpers ----
#define MMGRID(aa, bb) {                                                                  \
    _Pragma("unroll") for (int i_ = 0; i_ < 4; ++i_)                                      \
        _Pragma("unroll") for (int j_ = 0; j_ < 4; ++j_)                                  \
            acc[i_][j_] = __builtin_amdgcn_mfma_f32_16x16x32_bf16(aa[i_], bb[j_], acc[i_][j_], 0, 0, 0); }

// stage one 128x32 A-slab + 128x32 B-slab (16 chunks of 1 KB) into LDS; wave w stages 4 chunks
__device__ __forceinline__ void stage_tile(const short* __restrict__ Ap, const short* __restrict__ Bp,
                                           short* Asb, short* Bsb,
                                           int bm, int bn, int s, int KTOT, int wave, int lane){
    int c0 = wave * 2;
    gld_lds16(Ap + ((size_t)(bm * 8 + c0)     * KTOT + s) * 512 + lane * 8, Asb + (c0)     * 512);
    gld_lds16(Ap + ((size_t)(bm * 8 + c0 + 1) * KTOT + s) * 512 + lane * 8, Asb + (c0 + 1) * 512);
    gld_lds16(Bp + ((size_t)(bn * 8 + c0)     * KTOT + s) * 512 + lane * 8, Bsb + (c0)     * 512);
    gld_lds16(Bp + ((size_t)(bn * 8 + c0 + 1) * KTOT + s) * 512 + lane * 8, Bsb + (c0 + 1) * 512);
}

#define COMPUTE_STAGE(Abase, Bbase) {                                        \
    bf16x8 af[4], bfr[4];                                                    \
    _Pragma("unroll") for (int i_ = 0; i_ < 4; ++i_)                         \
        af[i_] = *(const bf16x8*)((Abase) + (wm * 4 + i_) * 512 + lane * 8); \
    _Pragma("unroll") for (int j_ = 0; j_ < 4; ++j_)                         \
        bfr[j_] = *(const bf16x8*)((Bbase) + (wn * 4 + j_) * 512 + lane * 8);\
    MMGRID(af, bfr); }

// ---------------- GEMM1 (MFMA+LDS dbuf): dXp = A1p @ Wx2p, output repacked as gemm2-A (KT2=16) ----------------
// M=16384, N=512, K=1024. 128x128 tiles.
__global__ __launch_bounds__(256) void gemm1_lds(
    const short* __restrict__ Ap, const short* __restrict__ Bp,
    short* __restrict__ dXp){
    const int KTOT = 32;
    __shared__ __align__(16) short Asb[2][4096];
    __shared__ __align__(16) short Bsb[2][4096];
    int tid = threadIdx.x;
    int wave = tid >> 6, lane = tid & 63;
    int wm = wave >> 1, wn = wave & 1;
    int bm = blockIdx.y, bn = blockIdx.x;
    int lhi = lane >> 4, llo = lane & 15;
    f32x4 acc[4][4];
    #pragma unroll
    for (int i = 0; i < 4; ++i)
        #pragma unroll
        for (int j = 0; j < 4; ++j) acc[i][j] = (f32x4){0.f, 0.f, 0.f, 0.f};
    stage_tile(Ap, Bp, &Asb[0][0], &Bsb[0][0], bm, bn, 0, KTOT, wave, lane);
    int buf = 0;
    for (int s = 0; s < KTOT; ++s){
        __syncthreads();      // drains staging vmcnt + joins all waves' prior ds_reads
        if (s + 1 < KTOT)
            stage_tile(Ap, Bp, &Asb[buf ^ 1][0], &Bsb[buf ^ 1][0], bm, bn, s + 1, KTOT, wave, lane);
        COMPUTE_STAGE(&Asb[buf][0], &Bsb[buf][0]);
        buf ^= 1;
    }
    #pragma unroll
    for (int j = 0; j < 4; ++j){
        int e = bn * 128 + wn * 64 + j * 16 + llo;
        int kt2 = e >> 5, hi2 = (e >> 3) & 3, jj = e & 7;
        #pragma unroll
        for (int i = 0; i < 4; ++i){
            #pragma unroll
            for (int r = 0; r < 4; ++r){
                int m = bm * 128 + wm * 64 + i * 16 + lhi * 4 + r;
                int mt2 = m >> 4, lo2 = m & 15;
                dXp[(((size_t)mt2 * 16 + kt2) * 64 + hi2 * 16 + lo2) * 8 + jj] =
                    f2bf(acc[i][j][r]);
            }
        }
    }
}

// ---------------- GEMM2 (MFMA+LDS dbuf): Dz2 = dXp @ Wb1p ; fused tanh-difference reduction ----------------
// M=16384, N=2048, K=512. dacc[n] += sum_m w[m]*(tanh(zb+Dz2)-tanh(zb))
__global__ __launch_bounds__(256) void gemm2_lds(
    const short* __restrict__ Ap, const short* __restrict__ Bp,
    const float* __restrict__ Z2B, const float* __restrict__ TB,
    const float* __restrict__ wrow, float* __restrict__ dacc){
    const int KTOT = 16;
    __shared__ __align__(16) short Asb[2][4096];
    __shared__ __align__(16) short Bsb[2][4096];
    int tid = threadIdx.x;
    int wave = tid >> 6, lane = tid & 63;
    int wm = wave >> 1, wn = wave & 1;
    int bm = blockIdx.y, bn = blockIdx.x;
    int lhi = lane >> 4, llo = lane & 15;
    f32x4 acc[4][4];
    #pragma unroll
    for (int i = 0; i < 4; ++i)
        #pragma unroll
        for (int j = 0; j < 4; ++j) acc[i][j] = (f32x4){0.f, 0.f, 0.f, 0.f};
    stage_tile(Ap, Bp, &Asb[0][0], &Bsb[0][0], bm, bn, 0, KTOT, wave, lane);
    int buf = 0;
    for (int s = 0; s < KTOT; ++s){
        __syncthreads();
        if (s + 1 < KTOT)
            stage_tile(Ap, Bp, &Asb[buf ^ 1][0], &Bsb[buf ^ 1][0], bm, bn, s + 1, KTOT, wave, lane);
        COMPUTE_STAGE(&Asb[buf][0], &Bsb[buf][0]);
        buf ^= 1;
    }
    // fused epilogue: tanh difference against fp32 base tables
    int nj[4];
    #pragma unroll
    for (int j = 0; j < 4; ++j) nj[j] = bn * 128 + wn * 64 + j * 16 + llo;
    float part[4] = {0.f, 0.f, 0.f, 0.f};
    #pragma unroll
    for (int i = 0; i < 4; ++i){
        #pragma unroll
        for (int r = 0; r < 4; ++r){
            int m = bm * 128 + wm * 64 + i * 16 + lhi * 4 + r;
            float wr = wrow[m];
            int mloc = m & 255;
            const float* zrow = Z2B + (size_t)mloc * HBc;
            const float* trow = TB  + (size_t)mloc * HBc;
            #pragma unroll
            for (int j = 0; j < 4; ++j){
                float dz = acc[i][j][r];
                part[j] += wr * (fast_tanh(zrow[nj[j]] + dz) - trow[nj[j]]);
            }
        }
    }
    #pragma unroll
    for (int j = 0; j < 4; ++j){
        part[j] += __shfl_xor(part[j], 16);
        part[j] += __shfl_xor(part[j], 32);
    }
    __shared__ float redn[128];
    if (tid < 128) redn[tid] = 0.f;
    __syncthreads();
    if (lane < 16){
        #pragma unroll
        for (int j = 0; j < 4; ++j)
            atomicAdd(&redn[wn * 64 + j * 16 + llo], part[j]);
    }
    __syncthreads();
    if (tid < 128) atomicAdd(&dacc[bn * 128 + tid], redn[tid]);
}

// ---------------- si = dacc @ Wb2 (bb2 cancels exactly) ----------------
__global__ void out_kernel(const float* __restrict__ dacc, const float* __restrict__ Wb2,
                           float* __restrict__ out){
    __shared__ float red[4][64];
    int tid = threadIdx.x;
    int part = tid >> 6, g = tid & 63;
    float s = 0.f;
    for (int h = part * 512; h < (part + 1) * 512; ++h)
        s += dacc[h] * Wb2[(size_t)h * GOUTc + g];
    red[part][g] = s;
    __syncthreads();
    if (tid < 64)
        out[tid] = red[0][tid] + red[1][tid] + red[2][tid] + red[3][tid];
}

extern "C" void kernel_launch(void* const* d_in, const int* in_sizes, int n_in,
                              void* d_out, int out_size, void* d_ws, size_t ws_size,
                              hipStream_t stream){
    const float* X         = (const float*)d_in[0];
    const float* Y         = (const float*)d_in[1];
    const float* R         = (const float*)d_in[2];
    const float* stoich    = (const float*)d_in[3];
    const float* times_t   = (const float*)d_in[4];
    const float* times_tau = (const float*)d_in[5];
    const float* Wx1 = (const float*)d_in[6];
    const float* bx1 = (const float*)d_in[7];
    const float* Wx2 = (const float*)d_in[8];
    const float* bx2 = (const float*)d_in[9];
    const float* Wih = (const float*)d_in[10];
    const float* Whh = (const float*)d_in[11];
    const float* bh  = (const float*)d_in[12];
    const float* Wb1 = (const float*)d_in[13];
    const float* bb1 = (const float*)d_in[14];
    const float* Wb2 = (const float*)d_in[15];
    // d_in[16] = bb2: cancels in (nn_disp - nn), unused
    const int* kp  = (const int*)d_in[17];
    const int* kpp = (const int*)d_in[18];
    const int* qp  = (const int*)d_in[19];
    const int* qpp = (const int*)d_in[20];
    float* out = (float*)d_out;

    float* ws   = (float*)d_ws;
    float* hb0  = ws;                        // 512
    float* hb1  = ws + 512;                  // 512
    float* cY   = ws + 1024;                 // 2048
    float* dacc = ws + 3072;                 // 2048
    float* wrow = ws + 5120;                 // 64*256 = 16384
    float* SW   = ws + 21504;                // 64*1024 = 65536
    float* XW   = ws + 87040;                // 256*1024 = 262144
    float* T1   = ws + 349184;               // 256*1024 = 262144
    float* eXb  = ws + 611328;               // 256*512 = 131072
    float* Z2B  = ws + 742400;               // 256*2048 = 524288
    float* TB   = ws + 1266688;              // 256*2048 = 524288
    short* A1p  = (short*)(ws + 1790976);    // 16384*1024 bf16 = 8,388,608 float slots
    short* Wx2p = (short*)(ws + 10179584);   // 1024*512 bf16 = 262,144 float slots
    short* Wb1p = (short*)(ws + 10441728);   // 512*2048 bf16 = 524,288 float slots
    short* dXp  = (short*)(ws + 10966016);   // 16384*512 bf16 = 4,194,304 float slots
    // total ws use: 15,160,320 floats = 60.6 MB

    pack_static_kernel<<<1024, 256, 0, stream>>>(stoich, Wx1, Wx2, Wb1, SW, Wx2p, Wb1p);
    xwt1_kernel       <<<1024, 256, 0, stream>>>(X, Wx1, bx1, kpp, qpp, XW, T1);
    w_kernel          <<<64,   256, 0, stream>>>(X, R, stoich, kpp, qpp, wrow);
    rnn_init_kernel   <<<1,    512, 0, stream>>>(hb0);
    for (int s = 0; s < 8; ++s){
        const float* hc = (s & 1) ? hb1 : hb0;
        float*       hn = (s & 1) ? hb0 : hb1;
        rnn_step_kernel<<<8, 512, 0, stream>>>(Y, Wih, Whh, bh, kp, qp, hc, hn, s);
    }
    cy_kernel         <<<8,    256, 0, stream>>>(hb0, Wb1, bb1, cY, dacc);
    exbase_kernel     <<<dim3(2, 32),  256, 0, stream>>>(T1, Wx2, bx2, eXb);
    z2base_kernel     <<<dim3(8, 32),  256, 0, stream>>>(eXb, Wb1, cY, times_t, times_tau, kp, Z2B, TB);
    act_delta_kernel  <<<8192, 256, 0, stream>>>(XW, T1, SW, A1p);
    gemm1_lds         <<<dim3(4, 128),  256, 0, stream>>>(A1p, Wx2p, dXp);
    gemm2_lds         <<<dim3(16, 128), 256, 0, stream>>>(dXp, Wb1p, Z2B, TB, wrow, dacc);
    out_kernel        <<<1,    256, 0, stream>>>(dacc, Wb2, out);
}

// Round 5
// 393.380 us; speedup vs baseline: 2.3880x; 1.0489x over previous
//
#include <hip/hip_runtime.h>
#include <math.h>

// Shapes (fixed by the reference)
#define DXc   16
#define MRc   64
#define MBARc 256
#define NTc   9
#define DYc   8
#define HXc   1024
#define EXc   512
#define HRc   512
#define HBc   2048
#define GOUTc 64
#define TOTc  2049   // (NT-1)*MBAR + 1

using bf16x8 = __attribute__((ext_vector_type(8))) short;
using f32x4  = __attribute__((ext_vector_type(4))) float;

__device__ __forceinline__ float fast_tanh(float x){
    float e = __expf(2.0f * x);
    return 1.0f - 2.0f / (e + 1.0f);
}

// fp32 -> bf16 round-to-nearest-even (bit pattern in a short)
__device__ __forceinline__ short f2bf(float f){
    unsigned u = __builtin_bit_cast(unsigned, f);
    u = (u + 0x7FFFu + ((u >> 16) & 1u)) >> 16;
    return (short)u;
}

// ---------------- RNN step kernels ----------------
__global__ void rnn_init_kernel(float* __restrict__ h0){
    h0[threadIdx.x] = 0.f;   // 512 threads
}

// one scan step: h_next = tanh(y_t@Wih + h_cur@Whh + bh); pass-through if t out of range
__global__ __launch_bounds__(512) void rnn_step_kernel(
    const float* __restrict__ Y, const float* __restrict__ Wih,
    const float* __restrict__ Whh, const float* __restrict__ bh,
    const int* kptr, const int* qptr,
    const float* __restrict__ h_cur, float* __restrict__ h_next, int step){
    __shared__ float hs[HRc];
    __shared__ float psum[8][64];
    int tid = threadIdx.x;
    int o   = tid & 63;
    int seg = tid >> 6;                 // 0..7
    int out = blockIdx.x * 64 + o;
    int k = kptr[0], q = qptr[0];
    int t = k + 1 + step;
    hs[tid] = h_cur[tid];
    __syncthreads();
    if (t >= NTc){                      // uniform branch
        if (seg == 0) h_next[out] = hs[out];
        return;
    }
    int k0 = seg * 64;
    float a0 = 0.f, a1 = 0.f, a2 = 0.f, a3 = 0.f;
    #pragma unroll 4
    for (int kk = 0; kk < 64; kk += 4){
        a0 += hs[k0 + kk + 0] * Whh[(size_t)(k0 + kk + 0) * HRc + out];
        a1 += hs[k0 + kk + 1] * Whh[(size_t)(k0 + kk + 1) * HRc + out];
        a2 += hs[k0 + kk + 2] * Whh[(size_t)(k0 + kk + 2) * HRc + out];
        a3 += hs[k0 + kk + 3] * Whh[(size_t)(k0 + kk + 3) * HRc + out];
    }
    psum[seg][o] = (a0 + a1) + (a2 + a3);
    __syncthreads();
    if (seg == 0){
        float a = 0.f;
        #pragma unroll
        for (int r = 0; r < 8; ++r) a += psum[r][o];
        const float* y = Y + (q * NTc + t) * DYc;
        float z = bh[out];
        #pragma unroll
        for (int d = 0; d < DYc; ++d) z += y[d] * Wih[d * HRc + out];
        h_next[out] = fast_tanh(z + a);
    }
}

// ---------------- merged weight-prep: SW + pack Wx2 + pack Wb1 ----------------
__global__ void pack_static_kernel(const float* __restrict__ stoich, const float* __restrict__ Wx1,
                                   const float* __restrict__ Wx2, const float* __restrict__ Wb1,
                                   float* __restrict__ SW, short* __restrict__ Wx2p,
                                   short* __restrict__ Wb1p){
    int b = blockIdx.x, tid = threadIdx.x;
    if (b < 256){
        // SW[j][c] = stoich[:,j] @ Wx1, 64*1024 elems
        int idx = b * 256 + tid;
        int j = idx >> 10, c = idx & 1023;
        float acc = 0.f;
        #pragma unroll
        for (int d = 0; d < DXc; ++d) acc += stoich[d * MRc + j] * Wx1[d * HXc + c];
        SW[idx] = acc;
    } else if (b < 512){
        // pack Wx2 (1024x512) into B-fragment order, KTOT=32
        size_t grp = (size_t)(b - 256) * 256 + tid;    // 65536 groups
        int lane = grp & 63;
        size_t t2 = grp >> 6;
        int kt = t2 & 31, nt = t2 >> 5;
        int n  = nt * 16 + (lane & 15);
        int k0 = kt * 32 + ((lane >> 4) << 3);
        short o8[8];
        #pragma unroll
        for (int jj = 0; jj < 8; ++jj) o8[jj] = f2bf(Wx2[(size_t)(k0 + jj) * EXc + n]);
        *(bf16x8*)(Wx2p + grp * 8) = *(bf16x8*)o8;
    } else {
        // pack Wb1 rows 1..512 (512x2048) into B-fragment order, KTOT=16
        size_t grp = (size_t)(b - 512) * 256 + tid;    // 131072 groups
        int lane = grp & 63;
        size_t t2 = grp >> 6;
        int kt = t2 & 15, nt = t2 >> 4;
        int n  = nt * 16 + (lane & 15);
        int k0 = kt * 32 + ((lane >> 4) << 3);
        short o8[8];
        #pragma unroll
        for (int jj = 0; jj < 8; ++jj) o8[jj] = f2bf(Wb1[(size_t)(1 + k0 + jj) * HBc + n]);
        *(bf16x8*)(Wb1p + grp * 8) = *(bf16x8*)o8;
    }
}

// ---------------- w[j*256+m] = valid(j,m) * R_delta[m][j] ----------------
__global__ void w_kernel(const float* __restrict__ X, const float* __restrict__ R,
                         const float* __restrict__ stoich,
                         const int* kpptr, const int* qpptr, float* __restrict__ w){
    int j = blockIdx.x, m = threadIdx.x;
    int base = kpptr[0] * MBARc;
    int qp = qpptr[0];
    const float* xr = X + ((size_t)qp * TOTc + base + m) * DXc;
    bool valid = true;
    #pragma unroll
    for (int d = 0; d < DXc; ++d) valid = valid && (xr[d] + stoich[d * MRc + j] >= 0.f);
    size_t rb = (size_t)qp * TOTc * MRc;
    float rd = R[rb + (size_t)(base + 1 + m) * MRc + j] - R[rb + (size_t)(base + m) * MRc + j];
    w[j * MBARc + m] = valid ? rd : 0.f;
}

// ---------------- cY[h] = eY @ Wb1[513:1025] + bb1 ; also zero dacc ----------------
__global__ void cy_kernel(const float* __restrict__ eY, const float* __restrict__ Wb1,
                          const float* __restrict__ bb1, float* __restrict__ cY,
                          float* __restrict__ dacc){
    int h = blockIdx.x * 256 + threadIdx.x;   // 2048
    float acc = bb1[h];
    for (int e = 0; e < EXc; ++e) acc += eY[e] * Wb1[(size_t)(1 + EXc + e) * HBc + h];
    cY[h] = acc;
    dacc[h] = 0.f;
}

// ---------------- XW[m][c] = Xbase[m]@Wx1 + bx1 ; T1 = tanh(XW) ----------------
__global__ void xwt1_kernel(const float* __restrict__ X, const float* __restrict__ Wx1,
                            const float* __restrict__ bx1,
                            const int* kpptr, const int* qpptr,
                            float* __restrict__ XW, float* __restrict__ T1){
    int idx = blockIdx.x * 256 + threadIdx.x;   // 256*1024
    int m = idx >> 10, c = idx & 1023;
    int base = kpptr[0] * MBARc;
    const float* xr = X + ((size_t)qpptr[0] * TOTc + base + m) * DXc;
    float acc = bx1[c];
    #pragma unroll
    for (int d = 0; d < DXc; ++d) acc += xr[d] * Wx1[d * HXc + c];
    XW[idx] = acc;
    T1[idx] = fast_tanh(acc);
}

// ---------------- eXbase[m][e] = T1[m] @ Wx2 + bx2  (fp32, 256x512) ----------------
__global__ __launch_bounds__(256) void exbase_kernel(const float* __restrict__ T1,
                                                     const float* __restrict__ Wx2,
                                                     const float* __restrict__ bx2,
                                                     float* __restrict__ eXb){
    __shared__ float t1s[8 * 1024];
    int tid = threadIdx.x;
    int e = blockIdx.x * 256 + tid;
    int m0 = blockIdx.y * 8;
    #pragma unroll
    for (int l = 0; l < 32; ++l){
        int idx = tid + l * 256;
        t1s[idx] = T1[(size_t)(m0 + (idx >> 10)) * HXc + (idx & 1023)];
    }
    __syncthreads();
    float acc[8] = {};
    for (int kk = 0; kk < HXc; ++kk){
        float wv = Wx2[(size_t)kk * EXc + e];
        #pragma unroll
        for (int mm = 0; mm < 8; ++mm) acc[mm] += t1s[mm * 1024 + kk] * wv;
    }
    float be = bx2[e];
    #pragma unroll
    for (int mm = 0; mm < 8; ++mm) eXb[(size_t)(m0 + mm) * EXc + e] = acc[mm] + be;
}

// ---------------- TB[m][h] = tanh(eXbase[m]@Wb1[1:513] + t[m]*Wb1[0] + cY) ----------------
__global__ __launch_bounds__(256) void z2base_kernel(const float* __restrict__ eXb,
                                                     const float* __restrict__ Wb1,
                                                     const float* __restrict__ cY,
                                                     const float* __restrict__ times_t,
                                                     const float* __restrict__ times_tau,
                                                     const int* kptr,
                                                     float* __restrict__ TB){
    __shared__ float exs[8 * 512];
    int tid = threadIdx.x;
    int h = blockIdx.x * 256 + tid;
    int m0 = blockIdx.y * 8;
    #pragma unroll
    for (int l = 0; l < 16; ++l){
        int idx = tid + l * 256;
        exs[idx] = eXb[(size_t)(m0 + (idx >> 9)) * EXc + (idx & 511)];
    }
    __syncthreads();
    float acc[8] = {};
    for (int kk = 0; kk < EXc; ++kk){
        float wv = Wb1[(size_t)(1 + kk) * HBc + h];
        #pragma unroll
        for (int mm = 0; mm < 8; ++mm) acc[mm] += exs[mm * 512 + kk] * wv;
    }
    float tk = times_t[kptr[0]];
    float w0 = Wb1[h], cy = cY[h];
    #pragma unroll
    for (int mm = 0; mm < 8; ++mm){
        int m = m0 + mm;
        float z = acc[mm] + (tk + times_tau[m]) * w0 + cy;
        TB[(size_t)m * HBc + h] = fast_tanh(z);
    }
}

// ---------------- act_delta: A1p = bf16(tanh(XW+SW[j]) - T1), packed A-layout, KTOT=32 ----------------
__global__ void act_delta_kernel(const float* __restrict__ XW, const float* __restrict__ T1,
                                 const float* __restrict__ SW, short* __restrict__ A1p){
    size_t grp = (size_t)blockIdx.x * 256 + threadIdx.x;  // 2,097,152 groups
    int lane = grp & 63;
    size_t t2 = grp >> 6;      // = mt*32 + kt
    int kt = t2 & 31;
    int mt = (int)(t2 >> 5);              // 0..1023
    int m  = mt * 16 + (lane & 15);       // global row 0..16383
    int c0 = kt * 32 + ((lane >> 4) << 3);
    int j    = m >> 8;
    int mloc = m & 255;
    const float* xwr = XW + (size_t)mloc * HXc + c0;
    const float* t1r = T1 + (size_t)mloc * HXc + c0;
    const float* swr = SW + (size_t)j * HXc + c0;
    short o8[8];
    #pragma unroll
    for (int i = 0; i < 8; ++i)
        o8[i] = f2bf(fast_tanh(xwr[i] + swr[i]) - t1r[i]);
    *(bf16x8*)(A1p + grp * 8) = *(bf16x8*)o8;
}

// ---- MFMA helpers: 4x8 grid per wave (64x128 wave tile) ----
#define LDFRAG(aa, bb, kk) {                                                   \
    _Pragma("unroll") for (int i_ = 0; i_ < 4; ++i_)                           \
        aa[i_] = *(const bf16x8*)(Aw + ((size_t)i_ * KT + (kk)) * 512);        \
    _Pragma("unroll") for (int j_ = 0; j_ < 8; ++j_)                           \
        bb[j_] = *(const bf16x8*)(Bw + ((size_t)j_ * KT + (kk)) * 512); }
#define MMGRID(aa, bb) {                                                       \
    _Pragma("unroll") for (int i_ = 0; i_ < 4; ++i_)                           \
        _Pragma("unroll") for (int j_ = 0; j_ < 8; ++j_)                       \
            acc[i_][j_] = __builtin_amdgcn_mfma_f32_16x16x32_bf16(aa[i_], bb[j_], acc[i_][j_], 0, 0, 0); }

// ---------------- GEMM1: dXp = A1p @ Wx2p, 128x256 block tile, direct-global ----------------
// M=16384, N=512, K=1024. grid (bm=128, bn=2). Output repacked as gemm2-A (KT2=16).
__global__ __launch_bounds__(256, 2) void gemm1_reg(
    const short* __restrict__ Ap, const short* __restrict__ Bp,
    short* __restrict__ dXp){
    const int KT = 32;
    int tid = threadIdx.x;
    int wave = tid >> 6, lane = tid & 63;
    int wm = wave >> 1, wn = wave & 1;
    int bm = blockIdx.x, bn = blockIdx.y;
    int mt0 = bm * 8 + wm * 4;
    int nt0 = bn * 16 + wn * 8;
    int lhi = lane >> 4, llo = lane & 15;
    const short* Aw = Ap + (size_t)mt0 * KT * 512 + lane * 8;
    const short* Bw = Bp + (size_t)nt0 * KT * 512 + lane * 8;
    f32x4 acc[4][8];
    #pragma unroll
    for (int i = 0; i < 4; ++i)
        #pragma unroll
        for (int j = 0; j < 8; ++j) acc[i][j] = (f32x4){0.f, 0.f, 0.f, 0.f};
    bf16x8 a0[4], b0[8], a1[4], b1[8];
    LDFRAG(a0, b0, 0);
    for (int kt = 0; kt < KT - 2; kt += 2){
        LDFRAG(a1, b1, kt + 1);
        MMGRID(a0, b0);
        LDFRAG(a0, b0, kt + 2);
        MMGRID(a1, b1);
    }
    LDFRAG(a1, b1, KT - 1);
    MMGRID(a0, b0);
    MMGRID(a1, b1);
    // epilogue: write bf16 into gemm2's A-packed layout (KT2=16)
    #pragma unroll
    for (int j = 0; j < 8; ++j){
        int e = bn * 256 + wn * 128 + j * 16 + llo;
        int kt2 = e >> 5, hi2 = (e >> 3) & 3, jj = e & 7;
        #pragma unroll
        for (int i = 0; i < 4; ++i){
            #pragma unroll
            for (int r = 0; r < 4; ++r){
                int m = bm * 128 + wm * 64 + i * 16 + lhi * 4 + r;
                int mt2 = m >> 4, lo2 = m & 15;
                dXp[(((size_t)mt2 * 16 + kt2) * 64 + hi2 * 16 + lo2) * 8 + jj] =
                    f2bf(acc[i][j][r]);
            }
        }
    }
}

// ---------------- GEMM2: Dz2 = dXp @ Wb1p, 128x256 tile; fused tanh-identity epilogue ----------------
// M=16384, N=2048, K=512. grid (bm=128, bn=8).
// dacc[n] += sum_m w[m] * tdz*(1-tb^2)/(1+tb*tdz), tdz = tanh(Dz2), tb = TB[mloc][n]
__global__ __launch_bounds__(256, 2) void gemm2_reg(
    const short* __restrict__ Ap, const short* __restrict__ Bp,
    const float* __restrict__ TB, const float* __restrict__ wrow,
    float* __restrict__ dacc){
    const int KT = 16;
    int tid = threadIdx.x;
    int wave = tid >> 6, lane = tid & 63;
    int wm = wave >> 1, wn = wave & 1;
    int bm = blockIdx.x, bn = blockIdx.y;
    int mt0 = bm * 8 + wm * 4;
    int nt0 = bn * 16 + wn * 8;
    int lhi = lane >> 4, llo = lane & 15;
    const short* Aw = Ap + (size_t)mt0 * KT * 512 + lane * 8;
    const short* Bw = Bp + (size_t)nt0 * KT * 512 + lane * 8;
    f32x4 acc[4][8];
    #pragma unroll
    for (int i = 0; i < 4; ++i)
        #pragma unroll
        for (int j = 0; j < 8; ++j) acc[i][j] = (f32x4){0.f, 0.f, 0.f, 0.f};
    bf16x8 a0[4], b0[8], a1[4], b1[8];
    LDFRAG(a0, b0, 0);
    for (int kt = 0; kt < KT - 2; kt += 2){
        LDFRAG(a1, b1, kt + 1);
        MMGRID(a0, b0);
        LDFRAG(a0, b0, kt + 2);
        MMGRID(a1, b1);
    }
    LDFRAG(a1, b1, KT - 1);
    MMGRID(a0, b0);
    MMGRID(a1, b1);
    // fused epilogue: tanh(zb+dz)-tanh(zb) = tdz*(1-tb^2)/(1+tb*tdz)
    int nj[8];
    #pragma unroll
    for (int j = 0; j < 8; ++j) nj[j] = bn * 256 + wn * 128 + j * 16 + llo;
    float part[8] = {};
    #pragma unroll
    for (int i = 0; i < 4; ++i){
        #pragma unroll
        for (int r = 0; r < 4; ++r){
            int m = bm * 128 + wm * 64 + i * 16 + lhi * 4 + r;
            float wr = wrow[m];
            const float* trow = TB + (size_t)(m & 255) * HBc;
            #pragma unroll
            for (int j = 0; j < 8; ++j){
                float tb  = trow[nj[j]];
                float tdz = fast_tanh(acc[i][j][r]);
                float num = tdz * (1.0f - tb * tb);
                float den = 1.0f + tb * tdz;
                part[j] += wr * num * __builtin_amdgcn_rcpf(den);
            }
        }
    }
    #pragma unroll
    for (int j = 0; j < 8; ++j){
        part[j] += __shfl_xor(part[j], 16);
        part[j] += __shfl_xor(part[j], 32);
    }
    __shared__ float redn[256];
    redn[tid] = 0.f;
    __syncthreads();
    if (lane < 16){
        #pragma unroll
        for (int j = 0; j < 8; ++j)
            atomicAdd(&redn[wn * 128 + j * 16 + llo], part[j]);
    }
    __syncthreads();
    atomicAdd(&dacc[bn * 256 + tid], redn[tid]);
}

// ---------------- si = dacc @ Wb2 (bb2 cancels exactly) ----------------
__global__ void out_kernel(const float* __restrict__ dacc, const float* __restrict__ Wb2,
                           float* __restrict__ out){
    __shared__ float red[4][64];
    int tid = threadIdx.x;
    int part = tid >> 6, g = tid & 63;
    float s = 0.f;
    for (int h = part * 512; h < (part + 1) * 512; ++h)
        s += dacc[h] * Wb2[(size_t)h * GOUTc + g];
    red[part][g] = s;
    __syncthreads();
    if (tid < 64)
        out[tid] = red[0][tid] + red[1][tid] + red[2][tid] + red[3][tid];
}

extern "C" void kernel_launch(void* const* d_in, const int* in_sizes, int n_in,
                              void* d_out, int out_size, void* d_ws, size_t ws_size,
                              hipStream_t stream){
    const float* X         = (const float*)d_in[0];
    const float* Y         = (const float*)d_in[1];
    const float* R         = (const float*)d_in[2];
    const float* stoich    = (const float*)d_in[3];
    const float* times_t   = (const float*)d_in[4];
    const float* times_tau = (const float*)d_in[5];
    const float* Wx1 = (const float*)d_in[6];
    const float* bx1 = (const float*)d_in[7];
    const float* Wx2 = (const float*)d_in[8];
    const float* bx2 = (const float*)d_in[9];
    const float* Wih = (const float*)d_in[10];
    const float* Whh = (const float*)d_in[11];
    const float* bh  = (const float*)d_in[12];
    const float* Wb1 = (const float*)d_in[13];
    const float* bb1 = (const float*)d_in[14];
    const float* Wb2 = (const float*)d_in[15];
    // d_in[16] = bb2: cancels in (nn_disp - nn), unused
    const int* kp  = (const int*)d_in[17];
    const int* kpp = (const int*)d_in[18];
    const int* qp  = (const int*)d_in[19];
    const int* qpp = (const int*)d_in[20];
    float* out = (float*)d_out;

    float* ws   = (float*)d_ws;
    float* hb0  = ws;                        // 512
    float* hb1  = ws + 512;                  // 512
    float* cY   = ws + 1024;                 // 2048
    float* dacc = ws + 3072;                 // 2048
    float* wrow = ws + 5120;                 // 64*256 = 16384
    float* SW   = ws + 21504;                // 64*1024 = 65536
    float* XW   = ws + 87040;                // 256*1024 = 262144
    float* T1   = ws + 349184;               // 256*1024 = 262144
    float* eXb  = ws + 611328;               // 256*512 = 131072
    float* TB   = ws + 742400;               // 256*2048 = 524288
    short* A1p  = (short*)(ws + 1266688);    // 16384*1024 bf16 = 8,388,608 float slots
    short* Wx2p = (short*)(ws + 9655296);    // 1024*512 bf16 = 262,144 float slots
    short* Wb1p = (short*)(ws + 9917440);    // 512*2048 bf16 = 524,288 float slots
    short* dXp  = (short*)(ws + 10441728);   // 16384*512 bf16 = 4,194,304 float slots
    // total ws use: 14,636,032 floats = 58.5 MB

    pack_static_kernel<<<1024, 256, 0, stream>>>(stoich, Wx1, Wx2, Wb1, SW, Wx2p, Wb1p);
    xwt1_kernel       <<<1024, 256, 0, stream>>>(X, Wx1, bx1, kpp, qpp, XW, T1);
    w_kernel          <<<64,   256, 0, stream>>>(X, R, stoich, kpp, qpp, wrow);
    rnn_init_kernel   <<<1,    512, 0, stream>>>(hb0);
    for (int s = 0; s < 8; ++s){
        const float* hc = (s & 1) ? hb1 : hb0;
        float*       hn = (s & 1) ? hb0 : hb1;
        rnn_step_kernel<<<8, 512, 0, stream>>>(Y, Wih, Whh, bh, kp, qp, hc, hn, s);
    }
    cy_kernel         <<<8,    256, 0, stream>>>(hb0, Wb1, bb1, cY, dacc);
    exbase_kernel     <<<dim3(2, 32),  256, 0, stream>>>(T1, Wx2, bx2, eXb);
    z2base_kernel     <<<dim3(8, 32),  256, 0, stream>>>(eXb, Wb1, cY, times_t, times_tau, kp, TB);
    act_delta_kernel  <<<8192, 256, 0, stream>>>(XW, T1, SW, A1p);
    gemm1_reg         <<<dim3(128, 2), 256, 0, stream>>>(A1p, Wx2p, dXp);
    gemm2_reg         <<<dim3(128, 8), 256, 0, stream>>>(dXp, Wb1p, TB, wrow, dacc);
    out_kernel        <<<1,    256, 0, stream>>>(dacc, Wb2, out);
}